// Round 9
// baseline (558.793 us; speedup 1.0000x reference)
//
#include <hip/hip_runtime.h>
#include <hip/hip_bf16.h>
#include <stdint.h>

typedef unsigned short ushort_t;
typedef float   f32x4  __attribute__((ext_vector_type(4)));
typedef short   bf16x8 __attribute__((ext_vector_type(8)));

#define NSRC 8192
#define NTGT 16384

__device__ __forceinline__ ushort_t f2bf(float f){
  union { float f; uint32_t u; } v; v.f = f;
  uint32_t r = v.u + 0x7fffu + ((v.u >> 16) & 1u);
  return (ushort_t)(r >> 16);
}
__device__ __forceinline__ uint2 pack4(f32x4 v){
  uint2 r;
  r.x = (uint32_t)f2bf(v.x) | ((uint32_t)f2bf(v.y) << 16);
  r.y = (uint32_t)f2bf(v.z) | ((uint32_t)f2bf(v.w) << 16);
  return r;
}
__device__ __forceinline__ bf16x8 cvt8(f32x4 lo, f32x4 hi){
  union { uint4 u; bf16x8 h; } x;
  uint2 a = pack4(lo), b = pack4(hi);
  x.u = make_uint4(a.x, a.y, b.x, b.y);
  return x.h;
}
__device__ __forceinline__ uint4 asu4(bf16x8 v){ union { bf16x8 h; uint4 u; } x; x.h = v; return x.u; }
__device__ __forceinline__ float sum4(f32x4 v){ return v.x + v.y + v.z + v.w; }

// async global->LDS DMA, 16B per lane; LDS dest = uniform base + lane*16 (HW)
typedef __attribute__((address_space(1))) const uint32_t* gas_t;
typedef __attribute__((address_space(3))) uint32_t* las_t;
__device__ __forceinline__ void dma16(const void* g, void* l){
  __builtin_amdgcn_global_load_lds((gas_t)g, (las_t)l, 16, 0, 0);
}
#define SCHED_FENCE() __builtin_amdgcn_sched_barrier(0)

// ---------------- generic f32 -> bf16 transpose: D[c][r] = bf16(S[r][c]) (weights only) ----------------
__global__ __launch_bounds__(256) void k_wt(const float* __restrict__ S, ushort_t* __restrict__ D,
                                            int R, int C){
  __shared__ float tile[32][33];
  const int cb = blockIdx.x * 32, rb = blockIdx.y * 32;
  const int tx = threadIdx.x & 31, ty = threadIdx.x >> 5;
#pragma unroll
  for (int i = 0; i < 4; ++i)
    tile[ty + 8*i][tx] = S[(size_t)(rb + ty + 8*i) * C + cb + tx];
  __syncthreads();
#pragma unroll
  for (int i = 0; i < 4; ++i)
    D[(size_t)(cb + ty + 8*i) * R + rb + tx] = f2bf(tile[tx][ty + 8*i]);
}

// ---------------- pack H_source [8192 k][256 n] f32 -> MFMA-fragment-packed bf16 ----------------
__global__ __launch_bounds__(256) void k_packH(const float* __restrict__ S, ushort_t* __restrict__ D){
  int u = blockIdx.x * 4 + (threadIdx.x >> 6);   // 0..4095 = nb(16) x kb(256)
  int lane = threadIdx.x & 63;
  int nb = u >> 8, kb = u & 255;
  int fr = lane & 15, q = lane >> 4;
  ushort_t buf[8];
#pragma unroll
  for (int j = 0; j < 8; ++j)
    buf[j] = f2bf(S[(size_t)(kb * 32 + q * 8 + j) * 256 + nb * 16 + fr]);
  *(uint4*)&D[((size_t)nb * 256 + kb) * 512 + (size_t)lane * 8] = *(uint4*)buf;
}

// ---------------- B2p ones-fragment (nb=8): col 128 = 1.0 (colsum trick), cols 129..143 = 0 ----------------
__global__ void k_init_b2p_tail(ushort_t* __restrict__ B2p){
  int idx = blockIdx.x * 256 + threadIdx.x;      // 32768 slots = kb(512) x lane(64)
  int lane = idx & 63;
  int kb = idx >> 6;
  int fr = lane & 15;
  uint32_t v = (fr == 0) ? 0x3F803F80u : 0u;
  uint4 val = {v, v, v, v};
  *(uint4*)&B2p[((size_t)8 * 512 + kb) * 512 + (size_t)lane * 8] = val;
}

// ---------------- G1: P2[kc] = bf16(A) @ H  (BM=64, BN=256, BK=32, Ksplit=4) ----------------
// Counted-vmcnt pipeline: A f32 loads 2 iters ahead (HBM window ~2 iters); B DMA waited per iter
// via vmcnt(5) (leaves 4 A-loads + 1 Abf store in flight). Emits Abf + rowsum partials.
__global__ __launch_bounds__(256) void k_gemm1(const float* __restrict__ A,
    const ushort_t* __restrict__ B1p, float* __restrict__ P2, float* __restrict__ rowsumP,
    ushort_t* __restrict__ Abf){
  __shared__ ushort_t Bls[2][16 * 512];
  const int t = threadIdx.x;
  const int mb = blockIdx.x, kc = blockIdx.y;
  const size_t m0 = (size_t)mb * 64;
  const int k0 = kc * 2048;
  const int kb0 = k0 >> 5;

  const int w = t >> 6, lane = t & 63;
  const int wr = w >> 1, wc = w & 1;
  const int fr = lane & 15, q = lane >> 4;

  const float* pa0 = &A[(m0 + wr * 32 + fr) * (size_t)NSRC + k0 + q * 8];
  const float* pa1 = pa0 + (size_t)16 * NSRC;
  ushort_t* pw0 = &Abf[(m0 + wr * 32 + fr) * (size_t)NSRC + k0 + q * 8];
  ushort_t* pw1 = pw0 + (size_t)16 * NSRC;
  ushort_t* pw  = (wc == 0) ? pw0 : pw1;

  f32x4 acc[2][8];
  const f32x4 vz = {0.f, 0.f, 0.f, 0.f};
#pragma unroll
  for (int i = 0; i < 2; ++i)
#pragma unroll
    for (int j = 0; j < 8; ++j) acc[i][j] = vz;
  float rs0 = 0.f, rs1 = 0.f;

  // prologue: D(0) then A(0), A(1)  [emit order pinned]
#pragma unroll
  for (int i = 0; i < 4; ++i){
    int f = w * 4 + i;
    dma16(&B1p[((size_t)f * 256 + kb0) * 512 + (size_t)lane * 8], &Bls[0][f * 512]);
  }
  SCHED_FENCE();
  f32x4 c0a = *(const f32x4*)pa0,        c0b = *(const f32x4*)(pa0 + 4);
  f32x4 c1a = *(const f32x4*)pa1,        c1b = *(const f32x4*)(pa1 + 4);
  f32x4 d0a = *(const f32x4*)(pa0 + 32), d0b = *(const f32x4*)(pa0 + 36);
  f32x4 d1a = *(const f32x4*)(pa1 + 32), d1b = *(const f32x4*)(pa1 + 36);
  asm volatile("s_waitcnt vmcnt(8)" ::: "memory");   // retire D(0); A(0),A(1) stay in flight
  SCHED_FENCE();
  __builtin_amdgcn_s_barrier();

  for (int kt = 0; kt < 64; ++kt){
    const int cur = kt & 1;
    // consume A(kt)
    rs0 += sum4(c0a) + sum4(c0b);
    rs1 += sum4(c1a) + sum4(c1b);
    bf16x8 af0 = cvt8(c0a, c0b);
    bf16x8 af1 = cvt8(c1a, c1b);

    // D(kt+1) -> other buffer  [pinned before A/store]
    if (kt < 63){
#pragma unroll
      for (int i = 0; i < 4; ++i){
        int f = w * 4 + i;
        dma16(&B1p[((size_t)f * 256 + kb0 + kt + 1) * 512 + (size_t)lane * 8],
              &Bls[cur ^ 1][f * 512]);
      }
    }
    SCHED_FENCE();
    // rotate A regs; issue A(kt+2)
    c0a = d0a; c0b = d0b; c1a = d1a; c1b = d1b;
    if (kt < 62){
      d0a = *(const f32x4*)(pa0 + (kt + 2) * 32); d0b = *(const f32x4*)(pa0 + (kt + 2) * 32 + 4);
      d1a = *(const f32x4*)(pa1 + (kt + 2) * 32); d1b = *(const f32x4*)(pa1 + (kt + 2) * 32 + 4);
    }
    // uniform Abf store (1 per wave)
    *(uint4*)&pw[kt * 32] = asu4(wc == 0 ? af0 : af1);

    // MFMA on tile kt from LDS
#pragma unroll
    for (int fn = 0; fn < 8; ++fn){
      bf16x8 bfv = *(bf16x8*)&Bls[cur][(wc * 8 + fn) * 512 + lane * 8];
      acc[0][fn] = __builtin_amdgcn_mfma_f32_16x16x32_bf16(af0, bfv, acc[0][fn], 0, 0, 0);
      acc[1][fn] = __builtin_amdgcn_mfma_f32_16x16x32_bf16(af1, bfv, acc[1][fn], 0, 0, 0);
    }
    asm volatile("s_waitcnt vmcnt(5)" ::: "memory");  // retire D(kt+1); leave A(kt+2)+store
    SCHED_FENCE();
    __builtin_amdgcn_s_barrier();
  }

  float* Pd = P2 + (size_t)kc * NTGT * 256;
#pragma unroll
  for (int fm = 0; fm < 2; ++fm)
#pragma unroll
    for (int j = 0; j < 4; ++j){
      int row = wr * 32 + fm * 16 + q * 4 + j;
#pragma unroll
      for (int fn = 0; fn < 8; ++fn)
        Pd[(m0 + row) * 256 + wc * 128 + fn * 16 + fr] = acc[fm][fn][j];
    }

  rs0 += __shfl_xor(rs0, 16); rs0 += __shfl_xor(rs0, 32);
  rs1 += __shfl_xor(rs1, 16); rs1 += __shfl_xor(rs1, 32);
  if (wc == 0 && q == 0){
    rowsumP[(size_t)kc * NTGT + m0 + wr * 32 + fr]      = rs0;
    rowsumP[(size_t)kc * NTGT + m0 + wr * 32 + 16 + fr] = rs1;
  }
}

// ---------------- G2: G2p[kc] = bf16(A)^T @ [h_tgt|1|0]  (BM=64, BN=144, BK=32, Ksplit=8) ----------------
// A^T bf16 scalar gathers 2 iters ahead; B DMA waited per iter via vmcnt(8).
__global__ __launch_bounds__(256) void k_gemm2(const ushort_t* __restrict__ Abf,
    const ushort_t* __restrict__ B2p, float* __restrict__ G2p){
  __shared__ ushort_t Bls[2][9 * 512];
  const int t = threadIdx.x;
  const int sb = blockIdx.x, kc = blockIdx.y;
  const size_t s0 = (size_t)sb * 64;
  const int k0 = kc * 2048;
  const int kb0 = k0 >> 5;

  const int w = t >> 6, lane = t & 63;
  const int fr = lane & 15, q = lane >> 4;
  const size_t scol = s0 + w * 16 + fr;
  const ushort_t* pA = &Abf[(size_t)(k0 + q * 8) * NSRC + scol];

  f32x4 acc[9];
  const f32x4 vz = {0.f, 0.f, 0.f, 0.f};
#pragma unroll
  for (int j = 0; j < 9; ++j) acc[j] = vz;

  // prologue: D(0) (wave w owns frags {w, w+4, w+8<9}), then A(0), A(1)
#pragma unroll
  for (int i = 0; i < 3; ++i){
    int f = w + i * 4;
    if (f < 9)
      dma16(&B2p[((size_t)f * 512 + kb0) * 512 + (size_t)lane * 8], &Bls[0][f * 512]);
  }
  SCHED_FENCE();
  ushort_t aN[8], aX[8];
#pragma unroll
  for (int j = 0; j < 8; ++j) aN[j] = pA[(size_t)j * NSRC];
#pragma unroll
  for (int j = 0; j < 8; ++j) aX[j] = pA[(size_t)(32 + j) * NSRC];
  asm volatile("s_waitcnt vmcnt(16)" ::: "memory");  // retire D(0); 16 A-loads in flight
  SCHED_FENCE();
  __builtin_amdgcn_s_barrier();

  for (int kt = 0; kt < 64; ++kt){
    const int cur = kt & 1;
    bf16x8 af;
#pragma unroll
    for (int j = 0; j < 8; ++j) af[j] = (short)aN[j];

    if (kt < 63){
#pragma unroll
      for (int i = 0; i < 3; ++i){
        int f = w + i * 4;
        if (f < 9)
          dma16(&B2p[((size_t)f * 512 + kb0 + kt + 1) * 512 + (size_t)lane * 8],
                &Bls[cur ^ 1][f * 512]);
      }
    }
    SCHED_FENCE();
#pragma unroll
    for (int j = 0; j < 8; ++j) aN[j] = aX[j];
    if (kt < 62){
#pragma unroll
      for (int j = 0; j < 8; ++j)
        aX[j] = pA[((size_t)(kt + 2) * 32 + j) * NSRC];
    }

#pragma unroll
    for (int fn = 0; fn < 9; ++fn){
      bf16x8 bfv = *(bf16x8*)&Bls[cur][fn * 512 + lane * 8];
      acc[fn] = __builtin_amdgcn_mfma_f32_16x16x32_bf16(af, bfv, acc[fn], 0, 0, 0);
    }
    asm volatile("s_waitcnt vmcnt(8)" ::: "memory");  // retire D(kt+1); leave 8 A-loads
    SCHED_FENCE();
    __builtin_amdgcn_s_barrier();
  }

  float* Pd = G2p + (size_t)kc * NSRC * 144;
#pragma unroll
  for (int j = 0; j < 4; ++j){
    int row = w * 16 + q * 4 + j;
#pragma unroll
    for (int fn = 0; fn < 9; ++fn)
      Pd[(s0 + row) * 144 + fn * 16 + fr] = acc[fn][j];
  }
}

// ---------------- G3: G3p[kc] = bf16(A) @ h_src  (BM=64, BN=128, BK=32, Ksplit=4) ----------------
// A bf16 16B loads 2 iters ahead; B DMA waited per iter via vmcnt(2).
__global__ __launch_bounds__(256) void k_gemm3(const ushort_t* __restrict__ Abf,
    const ushort_t* __restrict__ B3p, float* __restrict__ G3p){
  __shared__ ushort_t Bls[2][8 * 512];
  const int t = threadIdx.x;
  const int mb = blockIdx.x, kc = blockIdx.y;
  const size_t m0 = (size_t)mb * 64;
  const int k0 = kc * 2048;
  const int kb0 = k0 >> 5;

  const int w = t >> 6, lane = t & 63;
  const int wr = w >> 1, wc = w & 1;
  const int fr = lane & 15, q = lane >> 4;

  const ushort_t* pa0 = &Abf[(m0 + wr * 32 + fr) * (size_t)NSRC + k0 + q * 8];
  const ushort_t* pa1 = pa0 + (size_t)16 * NSRC;

  f32x4 acc[2][4];
  const f32x4 vz = {0.f, 0.f, 0.f, 0.f};
#pragma unroll
  for (int i = 0; i < 2; ++i)
#pragma unroll
    for (int j = 0; j < 4; ++j) acc[i][j] = vz;

#pragma unroll
  for (int i = 0; i < 2; ++i){
    int f = w * 2 + i;
    dma16(&B3p[((size_t)f * 256 + kb0) * 512 + (size_t)lane * 8], &Bls[0][f * 512]);
  }
  SCHED_FENCE();
  bf16x8 a0N = *(const bf16x8*)pa0;
  bf16x8 a1N = *(const bf16x8*)pa1;
  bf16x8 a0X = *(const bf16x8*)(pa0 + 32);
  bf16x8 a1X = *(const bf16x8*)(pa1 + 32);
  asm volatile("s_waitcnt vmcnt(4)" ::: "memory");   // retire D(0)
  SCHED_FENCE();
  __builtin_amdgcn_s_barrier();

  for (int kt = 0; kt < 64; ++kt){
    const int cur = kt & 1;
    bf16x8 u0 = a0N, u1 = a1N;

    if (kt < 63){
#pragma unroll
      for (int i = 0; i < 2; ++i){
        int f = w * 2 + i;
        dma16(&B3p[((size_t)f * 256 + kb0 + kt + 1) * 512 + (size_t)lane * 8],
              &Bls[cur ^ 1][f * 512]);
      }
    }
    SCHED_FENCE();
    a0N = a0X; a1N = a1X;
    if (kt < 62){
      a0X = *(const bf16x8*)(pa0 + (kt + 2) * 32);
      a1X = *(const bf16x8*)(pa1 + (kt + 2) * 32);
    }

#pragma unroll
    for (int fn = 0; fn < 4; ++fn){
      bf16x8 bfv = *(bf16x8*)&Bls[cur][(wc * 4 + fn) * 512 + lane * 8];
      acc[0][fn] = __builtin_amdgcn_mfma_f32_16x16x32_bf16(u0, bfv, acc[0][fn], 0, 0, 0);
      acc[1][fn] = __builtin_amdgcn_mfma_f32_16x16x32_bf16(u1, bfv, acc[1][fn], 0, 0, 0);
    }
    asm volatile("s_waitcnt vmcnt(2)" ::: "memory");  // retire D(kt+1); leave 2 A-loads
    SCHED_FENCE();
    __builtin_amdgcn_s_barrier();
  }

  float* Pd = G3p + (size_t)kc * NTGT * 128;
#pragma unroll
  for (int fm = 0; fm < 2; ++fm)
#pragma unroll
    for (int j = 0; j < 4; ++j){
      int row = wr * 32 + fm * 16 + q * 4 + j;
#pragma unroll
      for (int fn = 0; fn < 4; ++fn)
        Pd[(m0 + row) * 128 + wc * 64 + fn * 16 + fr] = acc[fm][fn][j];
    }
}

// ---------------- S1: h_tgt = relu(BN0((P/rowsum)@W0+b0)) -> B2p frags nb 0..7 ----------------
__global__ __launch_bounds__(256) void k_s1(
    const float* __restrict__ P2, const float* __restrict__ rowsumP,
    const ushort_t* __restrict__ W0t, const float* __restrict__ b0,
    const float* __restrict__ g, const float* __restrict__ be,
    const float* __restrict__ mu, const float* __restrict__ va,
    ushort_t* __restrict__ B2p)
{
  __shared__ ushort_t Xs[64 * 72];
  __shared__ ushort_t Ws[128 * 72];
  __shared__ float    os[64 * 132];
  __shared__ float invs[64], scs[128], mbs[128];
  const int t = threadIdx.x;
  const size_t m0 = (size_t)blockIdx.x * 64;
  const size_t CH = (size_t)NTGT * 256;

  if (t < 64){
    float rsv = rowsumP[m0 + t] + rowsumP[(size_t)NTGT + m0 + t]
              + rowsumP[2 * (size_t)NTGT + m0 + t] + rowsumP[3 * (size_t)NTGT + m0 + t];
    invs[t] = 1.0f / fmaxf(rsv, 1e-8f);
  } else if (t < 192){
    int n = t - 64;
    float s = g[n] * rsqrtf(va[n] + 1e-5f);
    scs[n] = s;
    mbs[n] = (b0[n] - mu[n]) * s + be[n];
  }
  __syncthreads();

  const int w = t >> 6, lane = t & 63;
  const int wr = w >> 1, wc = w & 1;
  const int fr = lane & 15, q = lane >> 4;
  f32x4 acc[2][4];
  const f32x4 vz = {0.f, 0.f, 0.f, 0.f};
#pragma unroll
  for (int i = 0; i < 2; ++i)
#pragma unroll
    for (int j = 0; j < 4; ++j) acc[i][j] = vz;

  for (int kt = 0; kt < 4; ++kt){
    const int kk = kt * 64;
    __syncthreads();
#pragma unroll
    for (int r = 0; r < 4; ++r){
      int c = t + 256 * r;
      int row = c >> 4, col4 = (c & 15) * 4;
      const float* pa = &P2[(m0 + row) * 256 + kk + col4];
      f32x4 v0 = *(const f32x4*)pa;
      f32x4 v1 = *(const f32x4*)(pa + CH);
      f32x4 v2 = *(const f32x4*)(pa + 2 * CH);
      f32x4 v3 = *(const f32x4*)(pa + 3 * CH);
      f32x4 v = (v0 + v1 + v2 + v3) * invs[row];
      *(uint2*)&Xs[row * 72 + col4] = pack4(v);
    }
#pragma unroll
    for (int r = 0; r < 4; ++r){
      int c = t + 256 * r;
      int n = c >> 3, k8 = (c & 7) * 8;
      *(uint4*)&Ws[n * 72 + k8] = *(const uint4*)&W0t[(size_t)n * 256 + kk + k8];
    }
    __syncthreads();
#pragma unroll
    for (int ks = 0; ks < 2; ++ks){
      bf16x8 af[2], bfv[4];
      af[0] = *(const bf16x8*)&Xs[(wr * 32 + fr) * 72 + ks * 32 + q * 8];
      af[1] = *(const bf16x8*)&Xs[(wr * 32 + 16 + fr) * 72 + ks * 32 + q * 8];
#pragma unroll
      for (int fn = 0; fn < 4; ++fn)
        bfv[fn] = *(const bf16x8*)&Ws[(wc * 64 + fn * 16 + fr) * 72 + ks * 32 + q * 8];
#pragma unroll
      for (int fm = 0; fm < 2; ++fm)
#pragma unroll
        for (int fn = 0; fn < 4; ++fn)
          acc[fm][fn] = __builtin_amdgcn_mfma_f32_16x16x32_bf16(af[fm], bfv[fn], acc[fm][fn], 0, 0, 0);
    }
  }

#pragma unroll
  for (int fm = 0; fm < 2; ++fm)
#pragma unroll
    for (int fn = 0; fn < 4; ++fn){
      int n = wc * 64 + fn * 16 + fr;
      float s = scs[n], mb = mbs[n];
#pragma unroll
      for (int j = 0; j < 4; ++j){
        int row = wr * 32 + fm * 16 + q * 4 + j;
        os[row * 132 + n] = fmaxf(acc[fm][fn][j] * s + mb, 0.f);
      }
    }
  __syncthreads();
  {
    const int kb0 = (int)(m0 >> 5);
#pragma unroll
    for (int r = 0; r < 4; ++r){
      int s = t + 256 * r;                 // 1024 slots = nb(8) x kb2(2) x lane(64)
      int lane2 = s & 63;
      int kb2 = (s >> 6) & 1;
      int nb = s >> 7;
      int fr2 = lane2 & 15, q2 = lane2 >> 4;
      int n = nb * 16 + fr2;
      ushort_t buf[8];
#pragma unroll
      for (int j = 0; j < 8; ++j)
        buf[j] = f2bf(os[(kb2 * 32 + q2 * 8 + j) * 132 + n]);
      *(uint4*)&B2p[((size_t)nb * 512 + kb0 + kb2) * 512 + (size_t)lane2 * 8] = *(uint4*)buf;
    }
  }
}

// ---------------- S2: h_src = relu(BNb((Q/colsum)@Wb0+bb0)) -> B3p frags nb 0..7 ----------------
__global__ __launch_bounds__(256) void k_s2(
    const float* __restrict__ G2p,
    const ushort_t* __restrict__ Wb0t, const float* __restrict__ bb0,
    const float* __restrict__ g, const float* __restrict__ be,
    const float* __restrict__ mu, const float* __restrict__ va,
    ushort_t* __restrict__ B3p)
{
  __shared__ ushort_t Xs[64 * 72];
  __shared__ ushort_t Ws[128 * 72];
  __shared__ float    os[64 * 132];
  __shared__ float invs[64], scs[128], mbs[128];
  const int t = threadIdx.x;
  const size_t m0 = (size_t)blockIdx.x * 64;
  const size_t CH = (size_t)NSRC * 144;

  if (t < 64){
    size_t row = m0 + t;
    float c = 0.f;
#pragma unroll
    for (int i = 0; i < 8; ++i) c += G2p[i * CH + row * 144 + 128];
    invs[t] = 1.0f / fmaxf(c, 1e-8f);
  } else if (t < 192){
    int n = t - 64;
    float s = g[n] * rsqrtf(va[n] + 1e-5f);
    scs[n] = s;
    mbs[n] = (bb0[n] - mu[n]) * s + be[n];
  }
  __syncthreads();

  const int w = t >> 6, lane = t & 63;
  const int wr = w >> 1, wc = w & 1;
  const int fr = lane & 15, q = lane >> 4;
  f32x4 acc[2][4];
  const f32x4 vz = {0.f, 0.f, 0.f, 0.f};
#pragma unroll
  for (int i = 0; i < 2; ++i)
#pragma unroll
    for (int j = 0; j < 4; ++j) acc[i][j] = vz;

  for (int kt = 0; kt < 2; ++kt){
    const int kk = kt * 64;
    __syncthreads();
#pragma unroll
    for (int r = 0; r < 4; ++r){
      int c = t + 256 * r;
      int row = c >> 4, col4 = (c & 15) * 4;
      const float* pa = &G2p[(m0 + row) * 144 + kk + col4];
      f32x4 v = {0.f, 0.f, 0.f, 0.f};
#pragma unroll
      for (int i = 0; i < 8; ++i) v += *(const f32x4*)(pa + i * CH);
      v *= invs[row];
      *(uint2*)&Xs[row * 72 + col4] = pack4(v);
    }
#pragma unroll
    for (int r = 0; r < 4; ++r){
      int c = t + 256 * r;
      int n = c >> 3, k8 = (c & 7) * 8;
      *(uint4*)&Ws[n * 72 + k8] = *(const uint4*)&Wb0t[(size_t)n * 128 + kk + k8];
    }
    __syncthreads();
#pragma unroll
    for (int ks = 0; ks < 2; ++ks){
      bf16x8 af[2], bfv[4];
      af[0] = *(const bf16x8*)&Xs[(wr * 32 + fr) * 72 + ks * 32 + q * 8];
      af[1] = *(const bf16x8*)&Xs[(wr * 32 + 16 + fr) * 72 + ks * 32 + q * 8];
#pragma unroll
      for (int fn = 0; fn < 4; ++fn)
        bfv[fn] = *(const bf16x8*)&Ws[(wc * 64 + fn * 16 + fr) * 72 + ks * 32 + q * 8];
#pragma unroll
      for (int fm = 0; fm < 2; ++fm)
#pragma unroll
        for (int fn = 0; fn < 4; ++fn)
          acc[fm][fn] = __builtin_amdgcn_mfma_f32_16x16x32_bf16(af[fm], bfv[fn], acc[fm][fn], 0, 0, 0);
    }
  }

#pragma unroll
  for (int fm = 0; fm < 2; ++fm)
#pragma unroll
    for (int fn = 0; fn < 4; ++fn){
      int n = wc * 64 + fn * 16 + fr;
      float s = scs[n], mb = mbs[n];
#pragma unroll
      for (int j = 0; j < 4; ++j){
        int row = wr * 32 + fm * 16 + q * 4 + j;
        os[row * 132 + n] = fmaxf(acc[fm][fn][j] * s + mb, 0.f);
      }
    }
  __syncthreads();
  {
    const int kb0 = (int)(m0 >> 5);
#pragma unroll
    for (int r = 0; r < 4; ++r){
      int s = t + 256 * r;
      int lane2 = s & 63;
      int kb2 = (s >> 6) & 1;
      int nb = s >> 7;
      int fr2 = lane2 & 15, q2 = lane2 >> 4;
      int n = nb * 16 + fr2;
      ushort_t buf[8];
#pragma unroll
      for (int j = 0; j < 8; ++j)
        buf[j] = f2bf(os[(kb2 * 32 + q2 * 8 + j) * 132 + n]);
      *(uint4*)&B3p[((size_t)nb * 256 + kb0 + kb2) * 512 + (size_t)lane2 * 8] = *(uint4*)buf;
    }
  }
}

// ---------------- S3: y=relu(BN1((R/rowsum)@W1+b1)); out = y@Wout + bout ----------------
__global__ __launch_bounds__(256) void k_s3(
    const float* __restrict__ G3p, const float* __restrict__ rowsumP,
    const ushort_t* __restrict__ W1t, const float* __restrict__ b1,
    const float* __restrict__ g, const float* __restrict__ be,
    const float* __restrict__ mu, const float* __restrict__ va,
    const ushort_t* __restrict__ Woutt, const float* __restrict__ bout,
    float* __restrict__ out)
{
  __shared__ ushort_t Xs[64 * 72];
  __shared__ ushort_t Ws[128 * 72];
  __shared__ ushort_t ys[64 * 136];
  __shared__ ushort_t Ws2[64 * 136];
  __shared__ float invs[64], scs[128], mbs[128];
  const int t = threadIdx.x;
  const size_t m0 = (size_t)blockIdx.x * 64;
  const size_t CH = (size_t)NTGT * 128;

  if (t < 64){
    float rsv = rowsumP[m0 + t] + rowsumP[(size_t)NTGT + m0 + t]
              + rowsumP[2 * (size_t)NTGT + m0 + t] + rowsumP[3 * (size_t)NTGT + m0 + t];
    invs[t] = 1.0f / fmaxf(rsv, 1e-8f);
  } else if (t < 192){
    int n = t - 64;
    float s = g[n] * rsqrtf(va[n] + 1e-5f);
    scs[n] = s;
    mbs[n] = (b1[n] - mu[n]) * s + be[n];
  }
#pragma unroll
  for (int r = 0; r < 4; ++r){
    int c = t + 256 * r;
    int n = c >> 4, k8 = (c & 15) * 8;
    *(uint4*)&Ws2[n * 136 + k8] = *(const uint4*)&Woutt[(size_t)n * 128 + k8];
  }
  __syncthreads();

  const int w = t >> 6, lane = t & 63;
  const int wr = w >> 1, wc = w & 1;
  const int fr = lane & 15, q = lane >> 4;
  f32x4 acc[2][4];
  const f32x4 vz = {0.f, 0.f, 0.f, 0.f};
#pragma unroll
  for (int i = 0; i < 2; ++i)
#pragma unroll
    for (int j = 0; j < 4; ++j) acc[i][j] = vz;

  for (int kt = 0; kt < 2; ++kt){
    const int kk = kt * 64;
    __syncthreads();
#pragma unroll
    for (int r = 0; r < 4; ++r){
      int c = t + 256 * r;
      int row = c >> 4, col4 = (c & 15) * 4;
      const float* pa = &G3p[(m0 + row) * 128 + kk + col4];
      f32x4 v0 = *(const f32x4*)pa;
      f32x4 v1 = *(const f32x4*)(pa + CH);
      f32x4 v2 = *(const f32x4*)(pa + 2 * CH);
      f32x4 v3 = *(const f32x4*)(pa + 3 * CH);
      f32x4 v = (v0 + v1 + v2 + v3) * invs[row];
      *(uint2*)&Xs[row * 72 + col4] = pack4(v);
    }
#pragma unroll
    for (int r = 0; r < 4; ++r){
      int c = t + 256 * r;
      int n = c >> 3, k8 = (c & 7) * 8;
      *(uint4*)&Ws[n * 72 + k8] = *(const uint4*)&W1t[(size_t)n * 128 + kk + k8];
    }
    __syncthreads();
#pragma unroll
    for (int ks = 0; ks < 2; ++ks){
      bf16x8 af[2], bfv[4];
      af[0] = *(const bf16x8*)&Xs[(wr * 32 + fr) * 72 + ks * 32 + q * 8];
      af[1] = *(const bf16x8*)&Xs[(wr * 32 + 16 + fr) * 72 + ks * 32 + q * 8];
#pragma unroll
      for (int fn = 0; fn < 4; ++fn)
        bfv[fn] = *(const bf16x8*)&Ws[(wc * 64 + fn * 16 + fr) * 72 + ks * 32 + q * 8];
#pragma unroll
      for (int fm = 0; fm < 2; ++fm)
#pragma unroll
        for (int fn = 0; fn < 4; ++fn)
          acc[fm][fn] = __builtin_amdgcn_mfma_f32_16x16x32_bf16(af[fm], bfv[fn], acc[fm][fn], 0, 0, 0);
    }
  }

#pragma unroll
  for (int fm = 0; fm < 2; ++fm)
#pragma unroll
    for (int fn = 0; fn < 4; ++fn){
      int n = wc * 64 + fn * 16 + fr;
      float s = scs[n], mb = mbs[n];
#pragma unroll
      for (int j = 0; j < 4; ++j){
        int row = wr * 32 + fm * 16 + q * 4 + j;
        ys[row * 136 + n] = f2bf(fmaxf(acc[fm][fn][j] * s + mb, 0.f));
      }
    }
  __syncthreads();

  f32x4 acc2[2][2];
#pragma unroll
  for (int i = 0; i < 2; ++i)
#pragma unroll
    for (int j = 0; j < 2; ++j) acc2[i][j] = vz;
#pragma unroll
  for (int ks = 0; ks < 4; ++ks){
    bf16x8 af[2], bfv[2];
    af[0] = *(const bf16x8*)&ys[(wr * 32 + fr) * 136 + ks * 32 + q * 8];
    af[1] = *(const bf16x8*)&ys[(wr * 32 + 16 + fr) * 136 + ks * 32 + q * 8];
#pragma unroll
    for (int fn = 0; fn < 2; ++fn)
      bfv[fn] = *(const bf16x8*)&Ws2[(wc * 32 + fn * 16 + fr) * 136 + ks * 32 + q * 8];
#pragma unroll
    for (int fm = 0; fm < 2; ++fm)
#pragma unroll
      for (int fn = 0; fn < 2; ++fn)
        acc2[fm][fn] = __builtin_amdgcn_mfma_f32_16x16x32_bf16(af[fm], bfv[fn], acc2[fm][fn], 0, 0, 0);
  }
#pragma unroll
  for (int fm = 0; fm < 2; ++fm)
#pragma unroll
    for (int fn = 0; fn < 2; ++fn){
      int n = wc * 32 + fn * 16 + fr;
      float bo = bout[n];
#pragma unroll
      for (int j = 0; j < 4; ++j){
        int row = wr * 32 + fm * 16 + q * 4 + j;
        out[(m0 + row) * 64 + n] = acc2[fm][fn][j] + bo;
      }
    }
}

// ---------------- launch ----------------
extern "C" void kernel_launch(void* const* d_in, const int* in_sizes, int n_in,
                              void* d_out, int out_size, void* d_ws, size_t ws_size,
                              hipStream_t stream) {
  const float* Hs  = (const float*)d_in[0];
  const float* A   = (const float*)d_in[2];
  const float* W0  = (const float*)d_in[3];
  const float* b0  = (const float*)d_in[4];
  const float* Wb0 = (const float*)d_in[5];
  const float* bb0 = (const float*)d_in[6];
  const float* W1  = (const float*)d_in[7];
  const float* b1  = (const float*)d_in[8];
  const float* bnfg= (const float*)d_in[9];
  const float* bnfb= (const float*)d_in[10];
  const float* bnfm= (const float*)d_in[11];
  const float* bnfv= (const float*)d_in[12];
  const float* bnbg= (const float*)d_in[13];
  const float* bnbb= (const float*)d_in[14];
  const float* bnbm= (const float*)d_in[15];
  const float* bnbv= (const float*)d_in[16];
  const float* Wout= (const float*)d_in[17];
  const float* bout= (const float*)d_in[18];
  float* out = (float*)d_out;

  char* ws = (char*)d_ws;
  // R1 (67MB): P2 (67MB, Ksplit4) -> G2p (37.7MB, Ksplit8) -> G3p (33.5MB, Ksplit4)
  float*    R1    = (float*)ws;
  constexpr size_t OFF_ABF  = 67108864;               // Abf: 16384*8192*2 = 256MB
  constexpr size_t OFF_B1P  = OFF_ABF + 268435456;    // B1p: 16*256*512*2
  constexpr size_t OFF_B2P  = OFF_B1P + 4194304;      // B2p: 9*512*512*2
  constexpr size_t OFF_B3P  = OFF_B2P + 4718592;      // B3p: 8*256*512*2
  constexpr size_t OFF_RS   = OFF_B3P + 2097152;      // rs: 4*16384*4
  constexpr size_t OFF_W0T  = OFF_RS  + 262144;
  constexpr size_t OFF_WB0T = OFF_W0T + 65536;
  constexpr size_t OFF_W1T  = OFF_WB0T + 32768;
  constexpr size_t OFF_WOT  = OFF_W1T + 32768;
  ushort_t* Abf  = (ushort_t*)(ws + OFF_ABF);
  ushort_t* B1p  = (ushort_t*)(ws + OFF_B1P);
  ushort_t* B2p  = (ushort_t*)(ws + OFF_B2P);
  ushort_t* B3p  = (ushort_t*)(ws + OFF_B3P);
  float*    rsP  = (float*)   (ws + OFF_RS);
  ushort_t* W0t  = (ushort_t*)(ws + OFF_W0T);
  ushort_t* Wb0t = (ushort_t*)(ws + OFF_WB0T);
  ushort_t* W1t  = (ushort_t*)(ws + OFF_W1T);
  ushort_t* Wott = (ushort_t*)(ws + OFF_WOT);

  k_packH<<<1024, 256, 0, stream>>>(Hs, B1p);
  k_wt<<<dim3(128/32, 256/32),  256, 0, stream>>>(W0,  W0t, 256, 128);
  k_wt<<<dim3(128/32, 128/32),  256, 0, stream>>>(Wb0, Wb0t, 128, 128);
  k_wt<<<dim3(128/32, 128/32),  256, 0, stream>>>(W1,  W1t, 128, 128);
  k_wt<<<dim3(64/32, 128/32),   256, 0, stream>>>(Wout, Wott, 128, 64);
  k_init_b2p_tail<<<128, 256, 0, stream>>>(B2p);

  k_gemm1<<<dim3(256, 4), 256, 0, stream>>>(A, B1p, R1, rsP, Abf);
  k_s1<<<256, 256, 0, stream>>>(R1, rsP, W0t, b0, bnfg, bnfb, bnfm, bnfv, B2p);
  k_gemm2<<<dim3(128, 8), 256, 0, stream>>>(Abf, B2p, R1);
  k_s2<<<128, 256, 0, stream>>>(R1, Wb0t, bb0, bnbg, bnbb, bnbm, bnbv, B3p);
  k_gemm3<<<dim3(256, 4), 256, 0, stream>>>(Abf, B3p, R1);
  k_s3<<<256, 256, 0, stream>>>(R1, rsP, W1t, b1, bnfg + 128, bnfb + 128, bnfm + 128, bnfv + 128,
                                Wott, bout, out);
}

// Round 10
// 488.084 us; speedup vs baseline: 1.1449x; 1.1449x over previous
//
#include <hip/hip_runtime.h>
#include <hip/hip_bf16.h>
#include <stdint.h>

typedef unsigned short ushort_t;
typedef float   f32x4  __attribute__((ext_vector_type(4)));
typedef short   bf16x8 __attribute__((ext_vector_type(8)));

#define NSRC 8192
#define NTGT 16384

__device__ __forceinline__ ushort_t f2bf(float f){
  union { float f; uint32_t u; } v; v.f = f;
  uint32_t r = v.u + 0x7fffu + ((v.u >> 16) & 1u);
  return (ushort_t)(r >> 16);
}
__device__ __forceinline__ uint2 pack4(f32x4 v){
  uint2 r;
  r.x = (uint32_t)f2bf(v.x) | ((uint32_t)f2bf(v.y) << 16);
  r.y = (uint32_t)f2bf(v.z) | ((uint32_t)f2bf(v.w) << 16);
  return r;
}
__device__ __forceinline__ bf16x8 cvt8(f32x4 lo, f32x4 hi){
  union { uint4 u; bf16x8 h; } x;
  uint2 a = pack4(lo), b = pack4(hi);
  x.u = make_uint4(a.x, a.y, b.x, b.y);
  return x.h;
}
__device__ __forceinline__ uint4 asu4(bf16x8 v){ union { bf16x8 h; uint4 u; } x; x.h = v; return x.u; }
__device__ __forceinline__ float sum4(f32x4 v){ return v.x + v.y + v.z + v.w; }

// async global->LDS DMA, 16B per lane; LDS dest = uniform base + lane*16 (HW)
typedef __attribute__((address_space(1))) const uint32_t* gas_t;
typedef __attribute__((address_space(3))) uint32_t* las_t;
__device__ __forceinline__ void dma16(const void* g, void* l){
  __builtin_amdgcn_global_load_lds((gas_t)g, (las_t)l, 16, 0, 0);
}
#define SCHED_FENCE() __builtin_amdgcn_sched_barrier(0)

// ---------------- generic f32 -> bf16 transpose: D[c][r] = bf16(S[r][c]) (weights only) ----------------
__global__ __launch_bounds__(256) void k_wt(const float* __restrict__ S, ushort_t* __restrict__ D,
                                            int R, int C){
  __shared__ float tile[32][33];
  const int cb = blockIdx.x * 32, rb = blockIdx.y * 32;
  const int tx = threadIdx.x & 31, ty = threadIdx.x >> 5;
#pragma unroll
  for (int i = 0; i < 4; ++i)
    tile[ty + 8*i][tx] = S[(size_t)(rb + ty + 8*i) * C + cb + tx];
  __syncthreads();
#pragma unroll
  for (int i = 0; i < 4; ++i)
    D[(size_t)(cb + ty + 8*i) * R + rb + tx] = f2bf(tile[tx][ty + 8*i]);
}

// ---------------- pack H_source [8192 k][256 n] f32 -> MFMA-fragment-packed bf16 ----------------
__global__ __launch_bounds__(256) void k_packH(const float* __restrict__ S, ushort_t* __restrict__ D){
  int u = blockIdx.x * 4 + (threadIdx.x >> 6);   // 0..4095 = nb(16) x kb(256)
  int lane = threadIdx.x & 63;
  int nb = u >> 8, kb = u & 255;
  int fr = lane & 15, q = lane >> 4;
  ushort_t buf[8];
#pragma unroll
  for (int j = 0; j < 8; ++j)
    buf[j] = f2bf(S[(size_t)(kb * 32 + q * 8 + j) * 256 + nb * 16 + fr]);
  *(uint4*)&D[((size_t)nb * 256 + kb) * 512 + (size_t)lane * 8] = *(uint4*)buf;
}

// ---------------- B2p ones-fragment (nb=8): col 128 = 1.0 (colsum trick), cols 129..143 = 0 ----------------
__global__ void k_init_b2p_tail(ushort_t* __restrict__ B2p){
  int idx = blockIdx.x * 256 + threadIdx.x;      // 32768 slots = kb(512) x lane(64)
  int lane = idx & 63;
  int kb = idx >> 6;
  int fr = lane & 15;
  uint32_t v = (fr == 0) ? 0x3F803F80u : 0u;
  uint4 val = {v, v, v, v};
  *(uint4*)&B2p[((size_t)8 * 512 + kb) * 512 + (size_t)lane * 8] = val;
}

// ---------------- G1: P2[kc] = bf16(A) @ H  (BM=128, BN=256, BK=32, Ksplit=4, 512 thr) ----------------
// Counted-vmcnt pipeline; 8 waves (wr=w>>1 in 0..3, wc=w&1). Emits Abf + rowsum partials.
__global__ __launch_bounds__(512) void k_gemm1(const float* __restrict__ A,
    const ushort_t* __restrict__ B1p, float* __restrict__ P2, float* __restrict__ rowsumP,
    ushort_t* __restrict__ Abf){
  __shared__ ushort_t Bls[2][16 * 512];
  const int t = threadIdx.x;
  const int mb = blockIdx.x, kc = blockIdx.y;
  const size_t m0 = (size_t)mb * 128;
  const int k0 = kc * 2048;
  const int kb0 = k0 >> 5;

  const int w = t >> 6, lane = t & 63;
  const int wr = w >> 1, wc = w & 1;
  const int fr = lane & 15, q = lane >> 4;

  const float* pa0 = &A[(m0 + wr * 32 + fr) * (size_t)NSRC + k0 + q * 8];
  const float* pa1 = pa0 + (size_t)16 * NSRC;
  ushort_t* pw0 = &Abf[(m0 + wr * 32 + fr) * (size_t)NSRC + k0 + q * 8];
  ushort_t* pw1 = pw0 + (size_t)16 * NSRC;
  ushort_t* pw  = (wc == 0) ? pw0 : pw1;

  f32x4 acc[2][8];
  const f32x4 vz = {0.f, 0.f, 0.f, 0.f};
#pragma unroll
  for (int i = 0; i < 2; ++i)
#pragma unroll
    for (int j = 0; j < 8; ++j) acc[i][j] = vz;
  float rs0 = 0.f, rs1 = 0.f;

  // prologue: D(0) (2 DMAs/wave) then A(0), A(1)
#pragma unroll
  for (int i = 0; i < 2; ++i){
    int f = w * 2 + i;
    dma16(&B1p[((size_t)f * 256 + kb0) * 512 + (size_t)lane * 8], &Bls[0][f * 512]);
  }
  SCHED_FENCE();
  f32x4 c0a = *(const f32x4*)pa0,        c0b = *(const f32x4*)(pa0 + 4);
  f32x4 c1a = *(const f32x4*)pa1,        c1b = *(const f32x4*)(pa1 + 4);
  f32x4 d0a = *(const f32x4*)(pa0 + 32), d0b = *(const f32x4*)(pa0 + 36);
  f32x4 d1a = *(const f32x4*)(pa1 + 32), d1b = *(const f32x4*)(pa1 + 36);
  asm volatile("s_waitcnt vmcnt(8)" ::: "memory");   // retire D(0); A(0),A(1) in flight
  SCHED_FENCE();
  __builtin_amdgcn_s_barrier();

  for (int kt = 0; kt < 64; ++kt){
    const int cur = kt & 1;
    rs0 += sum4(c0a) + sum4(c0b);
    rs1 += sum4(c1a) + sum4(c1b);
    bf16x8 af0 = cvt8(c0a, c0b);
    bf16x8 af1 = cvt8(c1a, c1b);

    if (kt < 63){
#pragma unroll
      for (int i = 0; i < 2; ++i){
        int f = w * 2 + i;
        dma16(&B1p[((size_t)f * 256 + kb0 + kt + 1) * 512 + (size_t)lane * 8],
              &Bls[cur ^ 1][f * 512]);
      }
    }
    SCHED_FENCE();
    c0a = d0a; c0b = d0b; c1a = d1a; c1b = d1b;
    if (kt < 62){
      d0a = *(const f32x4*)(pa0 + (kt + 2) * 32); d0b = *(const f32x4*)(pa0 + (kt + 2) * 32 + 4);
      d1a = *(const f32x4*)(pa1 + (kt + 2) * 32); d1b = *(const f32x4*)(pa1 + (kt + 2) * 32 + 4);
    }
    *(uint4*)&pw[kt * 32] = asu4(wc == 0 ? af0 : af1);

#pragma unroll
    for (int fn = 0; fn < 8; ++fn){
      bf16x8 bfv = *(bf16x8*)&Bls[cur][(wc * 8 + fn) * 512 + lane * 8];
      acc[0][fn] = __builtin_amdgcn_mfma_f32_16x16x32_bf16(af0, bfv, acc[0][fn], 0, 0, 0);
      acc[1][fn] = __builtin_amdgcn_mfma_f32_16x16x32_bf16(af1, bfv, acc[1][fn], 0, 0, 0);
    }
    asm volatile("s_waitcnt vmcnt(5)" ::: "memory");  // retire D(kt+1); leave 4 A-loads + 1 store
    SCHED_FENCE();
    __builtin_amdgcn_s_barrier();
  }

  float* Pd = P2 + (size_t)kc * NTGT * 256;
#pragma unroll
  for (int fm = 0; fm < 2; ++fm)
#pragma unroll
    for (int j = 0; j < 4; ++j){
      int row = wr * 32 + fm * 16 + q * 4 + j;
#pragma unroll
      for (int fn = 0; fn < 8; ++fn)
        Pd[(m0 + row) * 256 + wc * 128 + fn * 16 + fr] = acc[fm][fn][j];
    }

  rs0 += __shfl_xor(rs0, 16); rs0 += __shfl_xor(rs0, 32);
  rs1 += __shfl_xor(rs1, 16); rs1 += __shfl_xor(rs1, 32);
  if (wc == 0 && q == 0){
    rowsumP[(size_t)kc * NTGT + m0 + wr * 32 + fr]      = rs0;
    rowsumP[(size_t)kc * NTGT + m0 + wr * 32 + 16 + fr] = rs1;
  }
}

// ---------------- G2: G2p[kc] = bf16(A)^T @ [h_tgt|1|0]  (BM=128, BN=144, BK=32, Ksplit=8, 512 thr) ----------------
__global__ __launch_bounds__(512) void k_gemm2(const ushort_t* __restrict__ Abf,
    const ushort_t* __restrict__ B2p, float* __restrict__ G2p){
  __shared__ ushort_t Bls[2][9 * 512];
  const int t = threadIdx.x;
  const int sb = blockIdx.x, kc = blockIdx.y;
  const size_t s0 = (size_t)sb * 128;
  const int k0 = kc * 2048;
  const int kb0 = k0 >> 5;

  const int w = t >> 6, lane = t & 63;
  const int fr = lane & 15, q = lane >> 4;
  const size_t scol = s0 + w * 16 + fr;
  const ushort_t* pA = &Abf[(size_t)(k0 + q * 8) * NSRC + scol];

  f32x4 acc[9];
  const f32x4 vz = {0.f, 0.f, 0.f, 0.f};
#pragma unroll
  for (int j = 0; j < 9; ++j) acc[j] = vz;

  // prologue: D(0) (wave w owns frag w; wave 0 also frag 8), then A(0), A(1)
#pragma unroll
  for (int i = 0; i < 2; ++i){
    int f = w + i * 8;
    if (f < 9)
      dma16(&B2p[((size_t)f * 512 + kb0) * 512 + (size_t)lane * 8], &Bls[0][f * 512]);
  }
  SCHED_FENCE();
  ushort_t aN[8], aX[8];
#pragma unroll
  for (int j = 0; j < 8; ++j) aN[j] = pA[(size_t)j * NSRC];
#pragma unroll
  for (int j = 0; j < 8; ++j) aX[j] = pA[(size_t)(32 + j) * NSRC];
  asm volatile("s_waitcnt vmcnt(16)" ::: "memory");  // retire D(0); 16 A-loads in flight
  SCHED_FENCE();
  __builtin_amdgcn_s_barrier();

  for (int kt = 0; kt < 64; ++kt){
    const int cur = kt & 1;
    bf16x8 af;
#pragma unroll
    for (int j = 0; j < 8; ++j) af[j] = (short)aN[j];

    if (kt < 63){
#pragma unroll
      for (int i = 0; i < 2; ++i){
        int f = w + i * 8;
        if (f < 9)
          dma16(&B2p[((size_t)f * 512 + kb0 + kt + 1) * 512 + (size_t)lane * 8],
                &Bls[cur ^ 1][f * 512]);
      }
    }
    SCHED_FENCE();
#pragma unroll
    for (int j = 0; j < 8; ++j) aN[j] = aX[j];
    if (kt < 62){
#pragma unroll
      for (int j = 0; j < 8; ++j)
        aX[j] = pA[((size_t)(kt + 2) * 32 + j) * NSRC];
    }

#pragma unroll
    for (int fn = 0; fn < 9; ++fn){
      bf16x8 bfv = *(bf16x8*)&Bls[cur][fn * 512 + lane * 8];
      acc[fn] = __builtin_amdgcn_mfma_f32_16x16x32_bf16(af, bfv, acc[fn], 0, 0, 0);
    }
    asm volatile("s_waitcnt vmcnt(8)" ::: "memory");  // retire D(kt+1); leave 8 A-loads
    SCHED_FENCE();
    __builtin_amdgcn_s_barrier();
  }

  float* Pd = G2p + (size_t)kc * NSRC * 144;
#pragma unroll
  for (int j = 0; j < 4; ++j){
    int row = w * 16 + q * 4 + j;
#pragma unroll
    for (int fn = 0; fn < 9; ++fn)
      Pd[(s0 + row) * 144 + fn * 16 + fr] = acc[fn][j];
  }
}

// ---------------- G3: G3p[kc] = bf16(A) @ h_src  (BM=128, BN=128, BK=32, Ksplit=4, 512 thr) ----------------
__global__ __launch_bounds__(512) void k_gemm3(const ushort_t* __restrict__ Abf,
    const ushort_t* __restrict__ B3p, float* __restrict__ G3p){
  __shared__ ushort_t Bls[2][8 * 512];
  const int t = threadIdx.x;
  const int mb = blockIdx.x, kc = blockIdx.y;
  const size_t m0 = (size_t)mb * 128;
  const int k0 = kc * 2048;
  const int kb0 = k0 >> 5;

  const int w = t >> 6, lane = t & 63;
  const int wr = w >> 1, wc = w & 1;
  const int fr = lane & 15, q = lane >> 4;

  const ushort_t* pa0 = &Abf[(m0 + wr * 32 + fr) * (size_t)NSRC + k0 + q * 8];
  const ushort_t* pa1 = pa0 + (size_t)16 * NSRC;

  f32x4 acc[2][4];
  const f32x4 vz = {0.f, 0.f, 0.f, 0.f};
#pragma unroll
  for (int i = 0; i < 2; ++i)
#pragma unroll
    for (int j = 0; j < 4; ++j) acc[i][j] = vz;

  dma16(&B3p[((size_t)w * 256 + kb0) * 512 + (size_t)lane * 8], &Bls[0][w * 512]);
  SCHED_FENCE();
  bf16x8 a0N = *(const bf16x8*)pa0;
  bf16x8 a1N = *(const bf16x8*)pa1;
  bf16x8 a0X = *(const bf16x8*)(pa0 + 32);
  bf16x8 a1X = *(const bf16x8*)(pa1 + 32);
  asm volatile("s_waitcnt vmcnt(4)" ::: "memory");   // retire D(0)
  SCHED_FENCE();
  __builtin_amdgcn_s_barrier();

  for (int kt = 0; kt < 64; ++kt){
    const int cur = kt & 1;
    bf16x8 u0 = a0N, u1 = a1N;

    if (kt < 63){
      dma16(&B3p[((size_t)w * 256 + kb0 + kt + 1) * 512 + (size_t)lane * 8],
            &Bls[cur ^ 1][w * 512]);
    }
    SCHED_FENCE();
    a0N = a0X; a1N = a1X;
    if (kt < 62){
      a0X = *(const bf16x8*)(pa0 + (kt + 2) * 32);
      a1X = *(const bf16x8*)(pa1 + (kt + 2) * 32);
    }

#pragma unroll
    for (int fn = 0; fn < 4; ++fn){
      bf16x8 bfv = *(bf16x8*)&Bls[cur][(wc * 4 + fn) * 512 + lane * 8];
      acc[0][fn] = __builtin_amdgcn_mfma_f32_16x16x32_bf16(u0, bfv, acc[0][fn], 0, 0, 0);
      acc[1][fn] = __builtin_amdgcn_mfma_f32_16x16x32_bf16(u1, bfv, acc[1][fn], 0, 0, 0);
    }
    asm volatile("s_waitcnt vmcnt(2)" ::: "memory");  // retire D(kt+1); leave 2 A-loads
    SCHED_FENCE();
    __builtin_amdgcn_s_barrier();
  }

  float* Pd = G3p + (size_t)kc * NTGT * 128;
#pragma unroll
  for (int fm = 0; fm < 2; ++fm)
#pragma unroll
    for (int j = 0; j < 4; ++j){
      int row = wr * 32 + fm * 16 + q * 4 + j;
#pragma unroll
      for (int fn = 0; fn < 4; ++fn)
        Pd[(m0 + row) * 128 + wc * 64 + fn * 16 + fr] = acc[fm][fn][j];
    }
}

// ---------------- S1: h_tgt = relu(BN0((P/rowsum)@W0+b0)) -> B2p frags nb 0..7 ----------------
__global__ __launch_bounds__(256) void k_s1(
    const float* __restrict__ P2, const float* __restrict__ rowsumP,
    const ushort_t* __restrict__ W0t, const float* __restrict__ b0,
    const float* __restrict__ g, const float* __restrict__ be,
    const float* __restrict__ mu, const float* __restrict__ va,
    ushort_t* __restrict__ B2p)
{
  __shared__ ushort_t Xs[64 * 72];
  __shared__ ushort_t Ws[128 * 72];
  __shared__ float    os[64 * 132];
  __shared__ float invs[64], scs[128], mbs[128];
  const int t = threadIdx.x;
  const size_t m0 = (size_t)blockIdx.x * 64;
  const size_t CH = (size_t)NTGT * 256;

  if (t < 64){
    float rsv = rowsumP[m0 + t] + rowsumP[(size_t)NTGT + m0 + t]
              + rowsumP[2 * (size_t)NTGT + m0 + t] + rowsumP[3 * (size_t)NTGT + m0 + t];
    invs[t] = 1.0f / fmaxf(rsv, 1e-8f);
  } else if (t < 192){
    int n = t - 64;
    float s = g[n] * rsqrtf(va[n] + 1e-5f);
    scs[n] = s;
    mbs[n] = (b0[n] - mu[n]) * s + be[n];
  }
  __syncthreads();

  const int w = t >> 6, lane = t & 63;
  const int wr = w >> 1, wc = w & 1;
  const int fr = lane & 15, q = lane >> 4;
  f32x4 acc[2][4];
  const f32x4 vz = {0.f, 0.f, 0.f, 0.f};
#pragma unroll
  for (int i = 0; i < 2; ++i)
#pragma unroll
    for (int j = 0; j < 4; ++j) acc[i][j] = vz;

  for (int kt = 0; kt < 4; ++kt){
    const int kk = kt * 64;
    __syncthreads();
#pragma unroll
    for (int r = 0; r < 4; ++r){
      int c = t + 256 * r;
      int row = c >> 4, col4 = (c & 15) * 4;
      const float* pa = &P2[(m0 + row) * 256 + kk + col4];
      f32x4 v0 = *(const f32x4*)pa;
      f32x4 v1 = *(const f32x4*)(pa + CH);
      f32x4 v2 = *(const f32x4*)(pa + 2 * CH);
      f32x4 v3 = *(const f32x4*)(pa + 3 * CH);
      f32x4 v = (v0 + v1 + v2 + v3) * invs[row];
      *(uint2*)&Xs[row * 72 + col4] = pack4(v);
    }
#pragma unroll
    for (int r = 0; r < 4; ++r){
      int c = t + 256 * r;
      int n = c >> 3, k8 = (c & 7) * 8;
      *(uint4*)&Ws[n * 72 + k8] = *(const uint4*)&W0t[(size_t)n * 256 + kk + k8];
    }
    __syncthreads();
#pragma unroll
    for (int ks = 0; ks < 2; ++ks){
      bf16x8 af[2], bfv[4];
      af[0] = *(const bf16x8*)&Xs[(wr * 32 + fr) * 72 + ks * 32 + q * 8];
      af[1] = *(const bf16x8*)&Xs[(wr * 32 + 16 + fr) * 72 + ks * 32 + q * 8];
#pragma unroll
      for (int fn = 0; fn < 4; ++fn)
        bfv[fn] = *(const bf16x8*)&Ws[(wc * 64 + fn * 16 + fr) * 72 + ks * 32 + q * 8];
#pragma unroll
      for (int fm = 0; fm < 2; ++fm)
#pragma unroll
        for (int fn = 0; fn < 4; ++fn)
          acc[fm][fn] = __builtin_amdgcn_mfma_f32_16x16x32_bf16(af[fm], bfv[fn], acc[fm][fn], 0, 0, 0);
    }
  }

#pragma unroll
  for (int fm = 0; fm < 2; ++fm)
#pragma unroll
    for (int fn = 0; fn < 4; ++fn){
      int n = wc * 64 + fn * 16 + fr;
      float s = scs[n], mb = mbs[n];
#pragma unroll
      for (int j = 0; j < 4; ++j){
        int row = wr * 32 + fm * 16 + q * 4 + j;
        os[row * 132 + n] = fmaxf(acc[fm][fn][j] * s + mb, 0.f);
      }
    }
  __syncthreads();
  {
    const int kb0 = (int)(m0 >> 5);
#pragma unroll
    for (int r = 0; r < 4; ++r){
      int s = t + 256 * r;                 // 1024 slots = nb(8) x kb2(2) x lane(64)
      int lane2 = s & 63;
      int kb2 = (s >> 6) & 1;
      int nb = s >> 7;
      int fr2 = lane2 & 15, q2 = lane2 >> 4;
      int n = nb * 16 + fr2;
      ushort_t buf[8];
#pragma unroll
      for (int j = 0; j < 8; ++j)
        buf[j] = f2bf(os[(kb2 * 32 + q2 * 8 + j) * 132 + n]);
      *(uint4*)&B2p[((size_t)nb * 512 + kb0 + kb2) * 512 + (size_t)lane2 * 8] = *(uint4*)buf;
    }
  }
}

// ---------------- S2: h_src = relu(BNb((Q/colsum)@Wb0+bb0)) -> B3p frags nb 0..7 ----------------
__global__ __launch_bounds__(256) void k_s2(
    const float* __restrict__ G2p,
    const ushort_t* __restrict__ Wb0t, const float* __restrict__ bb0,
    const float* __restrict__ g, const float* __restrict__ be,
    const float* __restrict__ mu, const float* __restrict__ va,
    ushort_t* __restrict__ B3p)
{
  __shared__ ushort_t Xs[64 * 72];
  __shared__ ushort_t Ws[128 * 72];
  __shared__ float    os[64 * 132];
  __shared__ float invs[64], scs[128], mbs[128];
  const int t = threadIdx.x;
  const size_t m0 = (size_t)blockIdx.x * 64;
  const size_t CH = (size_t)NSRC * 144;

  if (t < 64){
    size_t row = m0 + t;
    float c = 0.f;
#pragma unroll
    for (int i = 0; i < 8; ++i) c += G2p[i * CH + row * 144 + 128];
    invs[t] = 1.0f / fmaxf(c, 1e-8f);
  } else if (t < 192){
    int n = t - 64;
    float s = g[n] * rsqrtf(va[n] + 1e-5f);
    scs[n] = s;
    mbs[n] = (bb0[n] - mu[n]) * s + be[n];
  }
  __syncthreads();

  const int w = t >> 6, lane = t & 63;
  const int wr = w >> 1, wc = w & 1;
  const int fr = lane & 15, q = lane >> 4;
  f32x4 acc[2][4];
  const f32x4 vz = {0.f, 0.f, 0.f, 0.f};
#pragma unroll
  for (int i = 0; i < 2; ++i)
#pragma unroll
    for (int j = 0; j < 4; ++j) acc[i][j] = vz;

  for (int kt = 0; kt < 2; ++kt){
    const int kk = kt * 64;
    __syncthreads();
#pragma unroll
    for (int r = 0; r < 4; ++r){
      int c = t + 256 * r;
      int row = c >> 4, col4 = (c & 15) * 4;
      const float* pa = &G2p[(m0 + row) * 144 + kk + col4];
      f32x4 v = {0.f, 0.f, 0.f, 0.f};
#pragma unroll
      for (int i = 0; i < 8; ++i) v += *(const f32x4*)(pa + i * CH);
      v *= invs[row];
      *(uint2*)&Xs[row * 72 + col4] = pack4(v);
    }
#pragma unroll
    for (int r = 0; r < 4; ++r){
      int c = t + 256 * r;
      int n = c >> 3, k8 = (c & 7) * 8;
      *(uint4*)&Ws[n * 72 + k8] = *(const uint4*)&Wb0t[(size_t)n * 128 + kk + k8];
    }
    __syncthreads();
#pragma unroll
    for (int ks = 0; ks < 2; ++ks){
      bf16x8 af[2], bfv[4];
      af[0] = *(const bf16x8*)&Xs[(wr * 32 + fr) * 72 + ks * 32 + q * 8];
      af[1] = *(const bf16x8*)&Xs[(wr * 32 + 16 + fr) * 72 + ks * 32 + q * 8];
#pragma unroll
      for (int fn = 0; fn < 4; ++fn)
        bfv[fn] = *(const bf16x8*)&Ws[(wc * 64 + fn * 16 + fr) * 72 + ks * 32 + q * 8];
#pragma unroll
      for (int fm = 0; fm < 2; ++fm)
#pragma unroll
        for (int fn = 0; fn < 4; ++fn)
          acc[fm][fn] = __builtin_amdgcn_mfma_f32_16x16x32_bf16(af[fm], bfv[fn], acc[fm][fn], 0, 0, 0);
    }
  }

#pragma unroll
  for (int fm = 0; fm < 2; ++fm)
#pragma unroll
    for (int fn = 0; fn < 4; ++fn){
      int n = wc * 64 + fn * 16 + fr;
      float s = scs[n], mb = mbs[n];
#pragma unroll
      for (int j = 0; j < 4; ++j){
        int row = wr * 32 + fm * 16 + q * 4 + j;
        os[row * 132 + n] = fmaxf(acc[fm][fn][j] * s + mb, 0.f);
      }
    }
  __syncthreads();
  {
    const int kb0 = (int)(m0 >> 5);
#pragma unroll
    for (int r = 0; r < 4; ++r){
      int s = t + 256 * r;
      int lane2 = s & 63;
      int kb2 = (s >> 6) & 1;
      int nb = s >> 7;
      int fr2 = lane2 & 15, q2 = lane2 >> 4;
      int n = nb * 16 + fr2;
      ushort_t buf[8];
#pragma unroll
      for (int j = 0; j < 8; ++j)
        buf[j] = f2bf(os[(kb2 * 32 + q2 * 8 + j) * 132 + n]);
      *(uint4*)&B3p[((size_t)nb * 256 + kb0 + kb2) * 512 + (size_t)lane2 * 8] = *(uint4*)buf;
    }
  }
}

// ---------------- S3: y=relu(BN1((R/rowsum)@W1+b1)); out = y@Wout + bout ----------------
__global__ __launch_bounds__(256) void k_s3(
    const float* __restrict__ G3p, const float* __restrict__ rowsumP,
    const ushort_t* __restrict__ W1t, const float* __restrict__ b1,
    const float* __restrict__ g, const float* __restrict__ be,
    const float* __restrict__ mu, const float* __restrict__ va,
    const ushort_t* __restrict__ Woutt, const float* __restrict__ bout,
    float* __restrict__ out)
{
  __shared__ ushort_t Xs[64 * 72];
  __shared__ ushort_t Ws[128 * 72];
  __shared__ ushort_t ys[64 * 136];
  __shared__ ushort_t Ws2[64 * 136];
  __shared__ float invs[64], scs[128], mbs[128];
  const int t = threadIdx.x;
  const size_t m0 = (size_t)blockIdx.x * 64;
  const size_t CH = (size_t)NTGT * 128;

  if (t < 64){
    float rsv = rowsumP[m0 + t] + rowsumP[(size_t)NTGT + m0 + t]
              + rowsumP[2 * (size_t)NTGT + m0 + t] + rowsumP[3 * (size_t)NTGT + m0 + t];
    invs[t] = 1.0f / fmaxf(rsv, 1e-8f);
  } else if (t < 192){
    int n = t - 64;
    float s = g[n] * rsqrtf(va[n] + 1e-5f);
    scs[n] = s;
    mbs[n] = (b1[n] - mu[n]) * s + be[n];
  }
#pragma unroll
  for (int r = 0; r < 4; ++r){
    int c = t + 256 * r;
    int n = c >> 4, k8 = (c & 15) * 8;
    *(uint4*)&Ws2[n * 136 + k8] = *(const uint4*)&Woutt[(size_t)n * 128 + k8];
  }
  __syncthreads();

  const int w = t >> 6, lane = t & 63;
  const int wr = w >> 1, wc = w & 1;
  const int fr = lane & 15, q = lane >> 4;
  f32x4 acc[2][4];
  const f32x4 vz = {0.f, 0.f, 0.f, 0.f};
#pragma unroll
  for (int i = 0; i < 2; ++i)
#pragma unroll
    for (int j = 0; j < 4; ++j) acc[i][j] = vz;

  for (int kt = 0; kt < 2; ++kt){
    const int kk = kt * 64;
    __syncthreads();
#pragma unroll
    for (int r = 0; r < 4; ++r){
      int c = t + 256 * r;
      int row = c >> 4, col4 = (c & 15) * 4;
      const float* pa = &G3p[(m0 + row) * 128 + kk + col4];
      f32x4 v0 = *(const f32x4*)pa;
      f32x4 v1 = *(const f32x4*)(pa + CH);
      f32x4 v2 = *(const f32x4*)(pa + 2 * CH);
      f32x4 v3 = *(const f32x4*)(pa + 3 * CH);
      f32x4 v = (v0 + v1 + v2 + v3) * invs[row];
      *(uint2*)&Xs[row * 72 + col4] = pack4(v);
    }
#pragma unroll
    for (int r = 0; r < 4; ++r){
      int c = t + 256 * r;
      int n = c >> 3, k8 = (c & 7) * 8;
      *(uint4*)&Ws[n * 72 + k8] = *(const uint4*)&W1t[(size_t)n * 128 + kk + k8];
    }
    __syncthreads();
#pragma unroll
    for (int ks = 0; ks < 2; ++ks){
      bf16x8 af[2], bfv[4];
      af[0] = *(const bf16x8*)&Xs[(wr * 32 + fr) * 72 + ks * 32 + q * 8];
      af[1] = *(const bf16x8*)&Xs[(wr * 32 + 16 + fr) * 72 + ks * 32 + q * 8];
#pragma unroll
      for (int fn = 0; fn < 4; ++fn)
        bfv[fn] = *(const bf16x8*)&Ws[(wc * 64 + fn * 16 + fr) * 72 + ks * 32 + q * 8];
#pragma unroll
      for (int fm = 0; fm < 2; ++fm)
#pragma unroll
        for (int fn = 0; fn < 4; ++fn)
          acc[fm][fn] = __builtin_amdgcn_mfma_f32_16x16x32_bf16(af[fm], bfv[fn], acc[fm][fn], 0, 0, 0);
    }
  }

#pragma unroll
  for (int fm = 0; fm < 2; ++fm)
#pragma unroll
    for (int fn = 0; fn < 4; ++fn){
      int n = wc * 64 + fn * 16 + fr;
      float s = scs[n], mb = mbs[n];
#pragma unroll
      for (int j = 0; j < 4; ++j){
        int row = wr * 32 + fm * 16 + q * 4 + j;
        ys[row * 136 + n] = f2bf(fmaxf(acc[fm][fn][j] * s + mb, 0.f));
      }
    }
  __syncthreads();

  f32x4 acc2[2][2];
#pragma unroll
  for (int i = 0; i < 2; ++i)
#pragma unroll
    for (int j = 0; j < 2; ++j) acc2[i][j] = vz;
#pragma unroll
  for (int ks = 0; ks < 4; ++ks){
    bf16x8 af[2], bfv[2];
    af[0] = *(const bf16x8*)&ys[(wr * 32 + fr) * 136 + ks * 32 + q * 8];
    af[1] = *(const bf16x8*)&ys[(wr * 32 + 16 + fr) * 136 + ks * 32 + q * 8];
#pragma unroll
    for (int fn = 0; fn < 2; ++fn)
      bfv[fn] = *(const bf16x8*)&Ws2[(wc * 32 + fn * 16 + fr) * 136 + ks * 32 + q * 8];
#pragma unroll
    for (int fm = 0; fm < 2; ++fm)
#pragma unroll
      for (int fn = 0; fn < 2; ++fn)
        acc2[fm][fn] = __builtin_amdgcn_mfma_f32_16x16x32_bf16(af[fm], bfv[fn], acc2[fm][fn], 0, 0, 0);
  }
#pragma unroll
  for (int fm = 0; fm < 2; ++fm)
#pragma unroll
    for (int fn = 0; fn < 2; ++fn){
      int n = wc * 32 + fn * 16 + fr;
      float bo = bout[n];
#pragma unroll
      for (int j = 0; j < 4; ++j){
        int row = wr * 32 + fm * 16 + q * 4 + j;
        out[(m0 + row) * 64 + n] = acc2[fm][fn][j] + bo;
      }
    }
}

// ---------------- launch ----------------
extern "C" void kernel_launch(void* const* d_in, const int* in_sizes, int n_in,
                              void* d_out, int out_size, void* d_ws, size_t ws_size,
                              hipStream_t stream) {
  const float* Hs  = (const float*)d_in[0];
  const float* A   = (const float*)d_in[2];
  const float* W0  = (const float*)d_in[3];
  const float* b0  = (const float*)d_in[4];
  const float* Wb0 = (const float*)d_in[5];
  const float* bb0 = (const float*)d_in[6];
  const float* W1  = (const float*)d_in[7];
  const float* b1  = (const float*)d_in[8];
  const float* bnfg= (const float*)d_in[9];
  const float* bnfb= (const float*)d_in[10];
  const float* bnfm= (const float*)d_in[11];
  const float* bnfv= (const float*)d_in[12];
  const float* bnbg= (const float*)d_in[13];
  const float* bnbb= (const float*)d_in[14];
  const float* bnbm= (const float*)d_in[15];
  const float* bnbv= (const float*)d_in[16];
  const float* Wout= (const float*)d_in[17];
  const float* bout= (const float*)d_in[18];
  float* out = (float*)d_out;

  char* ws = (char*)d_ws;
  // R1 (67MB): P2 (67MB, Ksplit4) -> G2p (37.7MB, Ksplit8) -> G3p (33.5MB, Ksplit4)
  float*    R1    = (float*)ws;
  constexpr size_t OFF_ABF  = 67108864;               // Abf: 16384*8192*2 = 256MB
  constexpr size_t OFF_B1P  = OFF_ABF + 268435456;    // B1p: 16*256*512*2
  constexpr size_t OFF_B2P  = OFF_B1P + 4194304;      // B2p: 9*512*512*2
  constexpr size_t OFF_B3P  = OFF_B2P + 4718592;      // B3p: 8*256*512*2
  constexpr size_t OFF_RS   = OFF_B3P + 2097152;      // rs: 4*16384*4
  constexpr size_t OFF_W0T  = OFF_RS  + 262144;
  constexpr size_t OFF_WB0T = OFF_W0T + 65536;
  constexpr size_t OFF_W1T  = OFF_WB0T + 32768;
  constexpr size_t OFF_WOT  = OFF_W1T + 32768;
  ushort_t* Abf  = (ushort_t*)(ws + OFF_ABF);
  ushort_t* B1p  = (ushort_t*)(ws + OFF_B1P);
  ushort_t* B2p  = (ushort_t*)(ws + OFF_B2P);
  ushort_t* B3p  = (ushort_t*)(ws + OFF_B3P);
  float*    rsP  = (float*)   (ws + OFF_RS);
  ushort_t* W0t  = (ushort_t*)(ws + OFF_W0T);
  ushort_t* Wb0t = (ushort_t*)(ws + OFF_WB0T);
  ushort_t* W1t  = (ushort_t*)(ws + OFF_W1T);
  ushort_t* Wott = (ushort_t*)(ws + OFF_WOT);

  k_packH<<<1024, 256, 0, stream>>>(Hs, B1p);
  k_wt<<<dim3(128/32, 256/32),  256, 0, stream>>>(W0,  W0t, 256, 128);
  k_wt<<<dim3(128/32, 128/32),  256, 0, stream>>>(Wb0, Wb0t, 128, 128);
  k_wt<<<dim3(128/32, 128/32),  256, 0, stream>>>(W1,  W1t, 128, 128);
  k_wt<<<dim3(64/32, 128/32),   256, 0, stream>>>(Wout, Wott, 128, 64);
  k_init_b2p_tail<<<128, 256, 0, stream>>>(B2p);

  k_gemm1<<<dim3(128, 4), 512, 0, stream>>>(A, B1p, R1, rsP, Abf);
  k_s1<<<256, 256, 0, stream>>>(R1, rsP, W0t, b0, bnfg, bnfb, bnfm, bnfv, B2p);
  k_gemm2<<<dim3(64, 8), 512, 0, stream>>>(Abf, B2p, R1);
  k_s2<<<128, 256, 0, stream>>>(R1, Wb0t, bb0, bnbg, bnbb, bnbm, bnbv, B3p);
  k_gemm3<<<dim3(128, 4), 512, 0, stream>>>(Abf, B3p, R1);
  k_s3<<<256, 256, 0, stream>>>(R1, rsP, W1t, b1, bnfg + 128, bnfb + 128, bnfm + 128, bnfv + 128,
                                Wott, bout, out);
}